// Round 3
// baseline (221.630 us; speedup 1.0000x reference)
//
#include <hip/hip_runtime.h>

// Head: fused single-head causal attention. Round 7: occupancy 2->3 waves/SIMD.
// One wave per batch element (64-thr blocks, grid=4096), zero barriers.
// LDS cut 17152->12032 B (qs dropped; q transposed through ps scratch, A-frags
// register-resident). VGPR cut to <=170 via __launch_bounds__(64,3):
// weights now a rolling 6+6 ping-pong (48 VGPR) reloaded from L2/L1-hot wf
// each kk-step; x staging is one fp32 tile in flight (32 VGPR) converted to
// bf16 just before re-issuing the buffer. -> 12 one-wave blocks/CU (was 8).
// Softmax: no max-sub (|s|<~3), scale folded into Wq; denominator via
// ones-column MFMA row-sum; P stored unnormalized, O divided at the end.
//
// mfma_f32_16x16x32_bf16 layouts (HW-verified, guide §3):
//   A-frag: A[m = lane&15][k = quad*8 + j]
//   B-frag: B[k = quad*8 + j][n = lane&15]
//   C/D   : col = lane&15, row = quad*4 + reg

#define TT 64
#define CC 128
#define HD 32

typedef __bf16 bf16_t;
typedef __bf16 bf8_t __attribute__((ext_vector_type(8)));
typedef __bf16 bf4_t __attribute__((ext_vector_type(4)));
typedef float  f4_t  __attribute__((ext_vector_type(4)));

// d_ws: wf[(n6*4 + kk)*64 + lane] = 16-byte bf8 B-frag.
// n6 = 0..5 (q lo/hi, k lo/hi, v lo/hi), kk = 0..3 (K blocks of 32).
// Element j = Wsel[(kk*32 + (lane>>4)*8 + j)][(n6&1)*16 + (lane&15)].
// Q-frags (n6<2) pre-scaled by 1/sqrt(32).
__global__ __launch_bounds__(256) void prep_weights(
    const float* __restrict__ Wq, const float* __restrict__ Wk,
    const float* __restrict__ Wv, bf16_t* __restrict__ wf)
{
  int t = blockIdx.x * 256 + threadIdx.x;   // 0..12287
  int j    = t & 7;
  int lane = (t >> 3) & 63;
  int kt   = (t >> 9) & 3;
  int n6   = t >> 11;
  int k    = kt * 32 + (lane >> 4) * 8 + j;
  int col  = (n6 & 1) * 16 + (lane & 15);
  const float* W = (n6 >> 1) == 0 ? Wq : ((n6 >> 1) == 1 ? Wk : Wv);
  float v = W[k * HD + col];
  if (n6 < 2) v *= 0.17677669529663687f;    // fold 1/sqrt(32) into Wq
  wf[t] = (bf16_t)v;
}

__global__ __launch_bounds__(64, 3) void head_fused(
    const float* __restrict__ x, const bf8_t* __restrict__ wf,
    float* __restrict__ out)
{
  __shared__ __align__(16) bf16_t ks[TT][40];   // k[row][d]          5120 B
  __shared__ __align__(16) bf16_t vt[HD][72];   // v^T[d][row]        4608 B
  __shared__ __align__(16) bf16_t ps[16][72];   // q-scratch / P strip 2304 B
  // total 12032 B; 13 blocks/CU by LDS, 12 by VGPR(<=170) -> 12 waves/CU

  const int lane = threadIdx.x;      // 0..63, one wave
  const int quad = lane >> 4;
  const int l16  = lane & 15;
  const int b    = blockIdx.x;
  const float* __restrict__ xblk = x + (size_t)b * (TT * CC);
  float* __restrict__ ob = out + (size_t)b * (TT * HD);

  const f4_t zero4 = {0.f, 0.f, 0.f, 0.f};

  bf8_t wA[6], wB[6];                // rolling weight ping-pong (48 VGPR)
  bf8_t aq[4];                       // q A-frags, register-resident (16 VGPR)
  float4 tf[8];                      // one x-tile in flight, fp32 (32 VGPR)

  auto wload = [&](bf8_t* w, int kkn) {
    #pragma unroll
    for (int n = 0; n < 6; ++n) w[n] = wf[(n * 4 + kkn) * 64 + lane];
  };
  // load half an x-tile (kk = 2h, 2h+1): 4x dwordx4
  auto load_half = [&](int i, int h) {
    #pragma unroll
    for (int kk = 2 * h; kk < 2 * h + 2; ++kk) {
      const float* s = xblk + (16 * i + l16) * CC + kk * 32 + quad * 8;
      tf[2 * kk]     = *(const float4*)s;
      tf[2 * kk + 1] = *(const float4*)(s + 4);
    }
  };
  auto cvt8 = [&](int kk) -> bf8_t {
    float4 f0 = tf[2 * kk], f1 = tf[2 * kk + 1];
    bf8_t a;
    a[0] = (bf16_t)f0.x; a[1] = (bf16_t)f0.y; a[2] = (bf16_t)f0.z; a[3] = (bf16_t)f0.w;
    a[4] = (bf16_t)f1.x; a[5] = (bf16_t)f1.y; a[6] = (bf16_t)f1.z; a[7] = (bf16_t)f1.w;
    return a;
  };

  // invariant: wA holds kk=0 frags on entry; restored on exit.
  auto proj_tile = [&](int i, int inext) {
    f4_t acc[6];
    #pragma unroll
    for (int n = 0; n < 6; ++n) acc[n] = zero4;
    bf8_t a;
    // kk = 0
    wload(wB, 1);
    a = cvt8(0);
    #pragma unroll
    for (int n = 0; n < 6; ++n)
      acc[n] = __builtin_amdgcn_mfma_f32_16x16x32_bf16(a, wA[n], acc[n], 0, 0, 0);
    // kk = 1
    wload(wA, 2);
    a = cvt8(1);
    #pragma unroll
    for (int n = 0; n < 6; ++n)
      acc[n] = __builtin_amdgcn_mfma_f32_16x16x32_bf16(a, wB[n], acc[n], 0, 0, 0);
    if (inext < 4) load_half(inext, 0);      // tf[0..3] consumed -> reissue
    // kk = 2
    wload(wB, 3);
    a = cvt8(2);
    #pragma unroll
    for (int n = 0; n < 6; ++n)
      acc[n] = __builtin_amdgcn_mfma_f32_16x16x32_bf16(a, wA[n], acc[n], 0, 0, 0);
    // kk = 3 (wrap weight prefetch to kk=0 for next tile)
    wload(wA, 0);
    a = cvt8(3);
    if (inext < 4) load_half(inext, 1);      // tf[4..7] consumed -> reissue
    #pragma unroll
    for (int n = 0; n < 6; ++n)
      acc[n] = __builtin_amdgcn_mfma_f32_16x16x32_bf16(a, wB[n], acc[n], 0, 0, 0);
    // stores: q -> ps scratch (transpose), k -> ks, v -> vt
    #pragma unroll
    for (int r = 0; r < 4; ++r) {
      int rl  = quad * 4 + r;                // C/D: row = quad*4 + reg
      int row = 16 * i + rl;
      ps[rl][l16]       = (bf16_t)acc[0][r];
      ps[rl][16 + l16]  = (bf16_t)acc[1][r];
      ks[row][l16]      = (bf16_t)acc[2][r];
      ks[row][16 + l16] = (bf16_t)acc[3][r];
    }
    bf4_t v0 = { (bf16_t)acc[4][0], (bf16_t)acc[4][1], (bf16_t)acc[4][2], (bf16_t)acc[4][3] };
    bf4_t v1 = { (bf16_t)acc[5][0], (bf16_t)acc[5][1], (bf16_t)acc[5][2], (bf16_t)acc[5][3] };
    *(bf4_t*)&vt[l16][16 * i + quad * 4]      = v0;   // tokens quad*4..+3 contiguous
    *(bf4_t*)&vt[16 + l16][16 * i + quad * 4] = v1;
    // q tile back out of scratch as A-frag (register-resident for phase 2)
    aq[i] = *(const bf8_t*)&ps[l16][quad * 8];
  };

  // scores -> exp (unnormalized, bf16) -> PV + ones-MFMA row-sum -> divide.
  // ps is reused as the P strip here (q-scratch use ended in phase 1).
  bf8_t ones8;
  #pragma unroll
  for (int t = 0; t < 8; ++t) ones8[t] = (bf16_t)1.0f;

  auto sm_tile = [&](int i) {
    f4_t sc[4];
    bf8_t aqv = aq[i];                       // scale pre-folded
    #pragma unroll
    for (int j = 0; j < 4; ++j) {
      sc[j] = zero4;
      if (j <= i) {
        bf8_t bk = *(const bf8_t*)&ks[16 * j + l16][quad * 8];
        sc[j] = __builtin_amdgcn_mfma_f32_16x16x32_bf16(aqv, bk, zero4, 0, 0, 0);
      }
    }
    #pragma unroll
    for (int r = 0; r < 4; ++r) {
      int rl = quad * 4 + r;
      #pragma unroll
      for (int j = 0; j < 4; ++j) {
        if (j <= i) {
          // no max-sub: |s| <= ~3 analytically, exp is safe; store raw exp
          bool valid = (j < i) | (l16 <= rl);  // diagonal-tile causal mask
          float e = __expf(sc[j][r]);
          ps[rl][j * 16 + l16] = (bf16_t)(valid ? e : 0.f);
        } else if (j == (i | 1)) {
          ps[rl][j * 16 + l16] = (bf16_t)0.f;  // zero-fill read range
        }
      }
    }
    f4_t o0 = zero4, o1 = zero4, osum = zero4;
    #pragma unroll
    for (int kk = 0; kk <= (i >> 1); ++kk) {     // skip all-zero K-tiles for i<2
      int k0 = kk * 32 + quad * 8;
      bf8_t ap  = *(const bf8_t*)&ps[l16][k0];
      bf8_t bv0 = *(const bf8_t*)&vt[l16][k0];
      bf8_t bv1 = *(const bf8_t*)&vt[16 + l16][k0];
      o0   = __builtin_amdgcn_mfma_f32_16x16x32_bf16(ap, bv0, o0, 0, 0, 0);
      o1   = __builtin_amdgcn_mfma_f32_16x16x32_bf16(ap, bv1, o1, 0, 0, 0);
      // D[m][n] = rowsum[m] for every n: each lane gets its row's denominator
      osum = __builtin_amdgcn_mfma_f32_16x16x32_bf16(ap, ones8, osum, 0, 0, 0);
    }
    #pragma unroll
    for (int r = 0; r < 4; ++r) {
      int row = 16 * i + quad * 4 + r;
      float inv = __builtin_amdgcn_rcpf(osum[r]);   // >= exp(diag) > 0
      ob[row * HD + l16]      = o0[r] * inv;
      ob[row * HD + 16 + l16] = o1[r] * inv;
    }
  };

  // ---------------- phase 1: pipelined projection ----------------
  load_half(0, 0); load_half(0, 1);  // x tile 0 (critical HBM stream first)
  wload(wA, 0);                      // weight frags kk=0 (L2-hot)
  proj_tile(0, 1);
  proj_tile(1, 2);
  proj_tile(2, 3);
  proj_tile(3, 4);
  // ---------------- phase 2: scores -> softmax -> PV ----------------
  sm_tile(0);
  sm_tile(1);
  sm_tile(2);
  sm_tile(3);
}

extern "C" void kernel_launch(void* const* d_in, const int* in_sizes, int n_in,
                              void* d_out, int out_size, void* d_ws, size_t ws_size,
                              hipStream_t stream) {
  const float* x  = (const float*)d_in[0];
  const float* Wq = (const float*)d_in[1];
  const float* Wk = (const float*)d_in[2];
  const float* Wv = (const float*)d_in[3];
  float* out = (float*)d_out;
  bf16_t* wf = (bf16_t*)d_ws;                  // 12288 bf16 = 24 KB
  int B = in_sizes[0] / (TT * CC);             // 4096

  prep_weights<<<dim3(48), dim3(256), 0, stream>>>(Wq, Wk, Wv, wf);
  head_fused<<<dim3(B), dim3(64), 0, stream>>>(x, (const bf8_t*)wf, out);
}